// Round 7
// baseline (231.686 us; speedup 1.0000x reference)
//
#include <hip/hip_runtime.h>
#include <hip/hip_bf16.h>
#include <hip/hip_cooperative_groups.h>
#include <math.h>

namespace cg = cooperative_groups;

#define B    16
#define SEQK 256
#define HID  128
#define NH   4
#define DK   32
#define DIM  64
#define OUTD 128

typedef __attribute__((ext_vector_type(8))) short short8;
typedef __attribute__((ext_vector_type(4))) float floatx4;

// phase-A roles (grid = 480)
#define NB_PROJ 384
#define NB_MVT  64
#define NB_WOB  32
#define NB_SETUP (NB_PROJ + NB_MVT + NB_WOB)
// phase-B attn blocks
#define NB_ATTN 256

__device__ __forceinline__ unsigned f2bf(float x) {
    union { float f; unsigned u; } v; v.f = x;
    return (v.u + 0x7FFFu + ((v.u >> 16) & 1u)) >> 16;   // RNE bf16
}

// phase: 0 = A + grid.sync + B (cooperative), 1 = A only, 2 = B only
__global__ __launch_bounds__(256, 2) void fused_kernel(
    const float* __restrict__ query, const float* __restrict__ key,
    const float* __restrict__ value, const int* __restrict__ mask,
    const float* __restrict__ Wq, const float* __restrict__ bq,
    const float* __restrict__ Wk, const float* __restrict__ bk,
    const float* __restrict__ Wo, const float* __restrict__ bo,
    float* __restrict__ qp, float* __restrict__ kp_t,
    unsigned* __restrict__ mvt_u, unsigned* __restrict__ wob_u,
    float* __restrict__ out, int phase)
{
    // shared arena: phase A uses 24.8 KB, phase B 48.4 KB
    __shared__ __align__(16) char smem_raw[48384];
    const int bid = blockIdx.x;
    const int t   = threadIdx.x;

    // ---------------- Phase A: projections + packs ----------------
    if (phase != 2) {
        if (bid < NB_PROJ) {
            float* in16 = (float*)smem_raw;          // [16][128]
            float* Wt   = in16 + 2048;               // [32][130]
            const int r0 = bid * 16;
            const bool isQ = (r0 < 2048);
            const float4* src4 = (const float4*)(isQ ? (query + r0 * 128)
                                                     : (key + (r0 - 2048) * 128));
            {
                float4* in4 = (float4*)in16;
                in4[t]       = src4[t];
                in4[t + 256] = src4[t + 256];
            }
            const float* Wsrc = isQ ? Wq : Wk;
            const int j  = t & 127;
            const int rg = (t >> 7) * 8;
            const float bias = isQ ? bq[j] : bk[j];
            float acc[8];
#pragma unroll
            for (int r = 0; r < 8; ++r) acc[r] = bias;

            for (int ic = 0; ic < 4; ++ic) {
                __syncthreads();
                {
                    const int i4 = t & 7, jg = t >> 3;
#pragma unroll
                    for (int jj = 0; jj < 4; ++jj) {
                        const int jw = jg + jj * 32;
                        const float4 w = *(const float4*)(Wsrc + jw * 128 + ic * 32 + i4 * 4);
                        Wt[(i4 * 4 + 0) * 130 + jw] = w.x;
                        Wt[(i4 * 4 + 1) * 130 + jw] = w.y;
                        Wt[(i4 * 4 + 2) * 130 + jw] = w.z;
                        Wt[(i4 * 4 + 3) * 130 + jw] = w.w;
                    }
                }
                __syncthreads();
#pragma unroll 2
                for (int i4 = 0; i4 < 8; ++i4) {
                    const float w0 = Wt[(i4 * 4 + 0) * 130 + j];
                    const float w1 = Wt[(i4 * 4 + 1) * 130 + j];
                    const float w2 = Wt[(i4 * 4 + 2) * 130 + j];
                    const float w3 = Wt[(i4 * 4 + 3) * 130 + j];
#pragma unroll
                    for (int r = 0; r < 8; ++r) {
                        const float4 xv = ((const float4*)(in16 + (rg + r) * 128))[ic * 8 + i4];
                        acc[r] = fmaf(xv.x, w0, fmaf(xv.y, w1, fmaf(xv.z, w2, fmaf(xv.w, w3, acc[r]))));
                    }
                }
            }

            if (isQ) {
                const float scale = 0.17677669529663687f;  // 1/sqrt(32) folded in
#pragma unroll
                for (int r = 0; r < 8; ++r) qp[(r0 + rg + r) * 128 + j] = acc[r] * scale;
            } else {
#pragma unroll
                for (int r = 0; r < 8; ++r) {
                    const int row = r0 - 2048 + rg + r;
                    const int bb = row >> 8, k = row & 255;
                    kp_t[(bb * 128 + j) * 256 + k] = acc[r];
                }
            }
        } else if (bid < NB_PROJ + NB_MVT) {
            // mvt pack: bf16 transposed mvt[b][c][k]; c<64 = m?v:0, c>=64 = m?1:0
            const int bb = (bid - NB_PROJ) >> 2, kt = (bid - NB_PROJ) & 3;
            const int c4 = t & 15, kp2 = t >> 4;
#pragma unroll
            for (int rr = 0; rr < 2; ++rr) {
                const int kpair = kp2 + rr * 16;
                const int k0 = kt * 64 + kpair * 2;
                const float4 v0 = *(const float4*)(value + (bb * 256 + k0) * 64 + c4 * 4);
                const float4 v1 = *(const float4*)(value + (bb * 256 + k0 + 1) * 64 + c4 * 4);
                const int4   m0 = *(const int4*)(mask + (bb * 256 + k0) * 64 + c4 * 4);
                const int4   m1 = *(const int4*)(mask + (bb * 256 + k0 + 1) * 64 + c4 * 4);
                const float a0[4] = {v0.x, v0.y, v0.z, v0.w};
                const float a1[4] = {v1.x, v1.y, v1.z, v1.w};
                const int   i0[4] = {m0.x, m0.y, m0.z, m0.w};
                const int   i1[4] = {m1.x, m1.y, m1.z, m1.w};
#pragma unroll
                for (int cc = 0; cc < 4; ++cc) {
                    const int c = c4 * 4 + cc;
                    const unsigned mv = (f2bf(i1[cc] ? a1[cc] : 0.f) << 16)
                                      |  f2bf(i0[cc] ? a0[cc] : 0.f);
                    const unsigned ff = ((i1[cc] ? 0x3F80u : 0u) << 16)
                                      |  (i0[cc] ? 0x3F80u : 0u);
                    mvt_u[(bb * 128 + c) * 128 + kt * 32 + kpair]      = mv;
                    mvt_u[(bb * 128 + 64 + c) * 128 + kt * 32 + kpair] = ff;
                }
            }
        } else {
            // Wo fp32 -> bf16, same [o][j] layout
            const int idx4 = (bid - NB_PROJ - NB_MVT) * 256 + t;   // 0..8191
            const float4 w = ((const float4*)Wo)[idx4];
            uint2 p;
            p.x = (f2bf(w.y) << 16) | f2bf(w.x);
            p.y = (f2bf(w.w) << 16) | f2bf(w.z);
            ((uint2*)wob_u)[idx4] = p;
        }
    }

    if (phase == 0) {
        __threadfence();
        cg::this_grid().sync();
    }
    if (phase == 1) return;
    if (bid >= NB_ATTN) return;

    // ---------------- Phase B: fused attention ----------------
    const short* mvt_s = (const short*)mvt_u;
    const short* wob_s = (const short*)wob_u;
    const int b  = bid & 15, qt = bid >> 4;
    const int q0 = qt * 8;
    const int h  = t >> 6, L = t & 63;

    float* qs = (float*)smem_raw;                    // [NH][32][12]  6144 B
    short* es = (short*)(smem_raw + 6144);           // [NH][16][264] 33792 B
    short* xs = (short*)(smem_raw + 6144 + 33792);   // [16][264]     8448 B

    if (phase == 0) __syncthreads();  // ensure phase-A smem use is done (paranoia)

    // stage q: qs[h][i][q] = qp_scaled[b*128+q0+q][h*32+i]
    {
        const int j = t & 127, qg = t >> 7;
        const int hh = j >> 5, ii = j & 31;
#pragma unroll
        for (int e = 0; e < 4; ++e) {
            const int q = qg * 4 + e;
            qs[hh * 384 + ii * 12 + q] = qp[(b * 128 + q0 + q) * 128 + j];
        }
    }
    __syncthreads();

    // G1: scores fp32. Lane L covers k = L*4..+4 for 8 q of its head.
    float s[8][4];
#pragma unroll
    for (int q = 0; q < 8; ++q)
#pragma unroll
        for (int kk = 0; kk < 4; ++kk) s[q][kk] = 0.f;
    {
        const float* kpb = kp_t + (b * 128 + h * 32) * 256 + L * 4;
        const float* qb  = qs + h * 384;
#pragma unroll 4
        for (int i = 0; i < 32; ++i) {
            const float4 kv = *(const float4*)(kpb + i * 256);
            const float4 qa = *(const float4*)(qb + i * 12);
            const float4 qc = *(const float4*)(qb + i * 12 + 4);
            const float qv[8] = {qa.x, qa.y, qa.z, qa.w, qc.x, qc.y, qc.z, qc.w};
            const float kw[4] = {kv.x, kv.y, kv.z, kv.w};
#pragma unroll
            for (int q = 0; q < 8; ++q)
#pragma unroll
                for (int kk = 0; kk < 4; ++kk)
                    s[q][kk] = fmaf(qv[q], kw[kk], s[q][kk]);
        }
    }

    // softmax per q: wave-wide max, exp, bf16 -> es (MFMA A-frag layout)
#pragma unroll
    for (int q = 0; q < 8; ++q) {
        float m = fmaxf(fmaxf(s[q][0], s[q][1]), fmaxf(s[q][2], s[q][3]));
#pragma unroll
        for (int off = 32; off > 0; off >>= 1) m = fmaxf(m, __shfl_xor(m, off, 64));
        const unsigned e01 = (f2bf(__expf(s[q][1] - m)) << 16) | f2bf(__expf(s[q][0] - m));
        const unsigned e23 = (f2bf(__expf(s[q][3] - m)) << 16) | f2bf(__expf(s[q][2] - m));
        *(uint2*)&es[h * 4224 + q * 264 + L * 4] = make_uint2(e01, e23);
    }
    // no barrier: es produced and consumed by the same wave

    // G2: PV via MFMA. D tiles 0..3 = num, 4..7 = den.
    const int lq = L & 15, lk = (L >> 4) * 8;
    floatx4 pv[8];
#pragma unroll
    for (int tt = 0; tt < 8; ++tt) pv[tt] = (floatx4){0.f, 0.f, 0.f, 0.f};
    {
        const short* eb = es + h * 4224 + lq * 264;
        const short* mb = mvt_s + (b * 128) * 256 + lk;
#pragma unroll
        for (int c8 = 0; c8 < 8; ++c8) {
            const short8 a = *(const short8*)(eb + c8 * 32 + lk);
#pragma unroll
            for (int tt = 0; tt < 8; ++tt) {
                const short8 bf = *(const short8*)(mb + (tt * 16 + lq) * 256 + c8 * 32);
                pv[tt] = __builtin_amdgcn_mfma_f32_16x16x32_bf16(a, bf, pv[tt], 0, 0, 0);
            }
        }
    }
    if ((L >> 4) < 2) {
#pragma unroll
        for (int tt = 0; tt < 4; ++tt)
#pragma unroll
            for (int r = 0; r < 4; ++r) {
                const int row = (L >> 4) * 4 + r;
                xs[row * 264 + h * 64 + tt * 16 + lq] =
                    (short)f2bf(pv[tt][r] / pv[tt + 4][r]);
            }
    }
    __syncthreads();

    // G3: O-projection via MFMA, full K=256 -> direct store (no atomics)
    floatx4 oa[2];
    oa[0] = (floatx4){0.f, 0.f, 0.f, 0.f};
    oa[1] = (floatx4){0.f, 0.f, 0.f, 0.f};
    {
        const short* xb = xs + lq * 264;
#pragma unroll
        for (int j8 = 0; j8 < 8; ++j8) {
            const short8 a = *(const short8*)(xb + j8 * 32 + lk);
#pragma unroll
            for (int w = 0; w < 2; ++w) {
                const int o = (h * 2 + w) * 16 + lq;
                const short8 bf = *(const short8*)(wob_s + o * 256 + j8 * 32 + lk);
                oa[w] = __builtin_amdgcn_mfma_f32_16x16x32_bf16(a, bf, oa[w], 0, 0, 0);
            }
        }
    }
    if ((L >> 4) < 2) {
#pragma unroll
        for (int w = 0; w < 2; ++w) {
            const int o = (h * 2 + w) * 16 + lq;
            const float bov = bo[o];
#pragma unroll
            for (int r = 0; r < 4; ++r) {
                const int row = (L >> 4) * 4 + r;
                out[(b * 128 + q0 + row) * 128 + o] = oa[w][r] + bov;
            }
        }
    }
}

extern "C" void kernel_launch(void* const* d_in, const int* in_sizes, int n_in,
                              void* d_out, int out_size, void* d_ws, size_t ws_size,
                              hipStream_t stream)
{
    const float* query = (const float*)d_in[0];
    const float* key   = (const float*)d_in[1];
    const float* value = (const float*)d_in[2];
    const int*   mask  = (const int*)d_in[3];
    const float* Wq    = (const float*)d_in[4];
    const float* bq    = (const float*)d_in[5];
    const float* Wk    = (const float*)d_in[6];
    const float* bk    = (const float*)d_in[7];
    const float* Wo    = (const float*)d_in[8];
    const float* bo    = (const float*)d_in[9];
    float* out = (float*)d_out;

    float* ws       = (float*)d_ws;
    float* qp       = ws;                           // 262144 f32
    float* kp_t     = qp + 262144;                  // 524288 f32
    unsigned* mvt_u = (unsigned*)(kp_t + 524288);   // 262144 u32
    unsigned* wob_u = mvt_u + 262144;               // 16384 u32

    int phase0 = 0;
    void* args[] = {
        (void*)&query, (void*)&key, (void*)&value, (void*)&mask,
        (void*)&Wq, (void*)&bq, (void*)&Wk, (void*)&bk, (void*)&Wo, (void*)&bo,
        (void*)&qp, (void*)&kp_t, (void*)&mvt_u, (void*)&wob_u, (void*)&out,
        (void*)&phase0
    };
    hipError_t err = hipLaunchCooperativeKernel((const void*)fused_kernel,
                                                dim3(NB_SETUP), dim3(256),
                                                args, 0, stream);
    if (err != hipSuccess) {
        // graceful fallback: two ordinary launches, no grid.sync executed
        fused_kernel<<<NB_SETUP, 256, 0, stream>>>(query, key, value, mask,
                                                   Wq, bq, Wk, bk, Wo, bo,
                                                   qp, kp_t, mvt_u, wob_u, out, 1);
        fused_kernel<<<NB_ATTN, 256, 0, stream>>>(query, key, value, mask,
                                                  Wq, bq, Wk, bk, Wo, bo,
                                                  qp, kp_t, mvt_u, wob_u, out, 2);
    }
}

// Round 8
// 108.760 us; speedup vs baseline: 2.1302x; 2.1302x over previous
//
#include <hip/hip_runtime.h>
#include <hip/hip_bf16.h>
#include <math.h>

#define B    16
#define SEQK 256
#define HID  128
#define NH   4
#define DK   32
#define DIM  64
#define OUTD 128

typedef __attribute__((ext_vector_type(8))) short short8;
typedef __attribute__((ext_vector_type(4))) float floatx4;

// setup roles
#define NB_PROJ 384
#define NB_MVT  64
#define NB_WOB  32
#define NB_SETUP (NB_PROJ + NB_MVT + NB_WOB)

__device__ __forceinline__ unsigned f2bf(float x) {
    union { float f; unsigned u; } v; v.f = x;
    return (v.u + 0x7FFFu + ((v.u >> 16) & 1u)) >> 16;   // RNE bf16
}

// ---------------------------------------------------------------------------
// setup (identical to R6's verified version): (a) Q/K projection with in-LDS
// weight transpose, (b) mvt bf16 pack-transpose, (c) Wo -> bf16.
__global__ __launch_bounds__(256) void setup_kernel(
    const float* __restrict__ query, const float* __restrict__ key,
    const float* __restrict__ value, const int* __restrict__ mask,
    const float* __restrict__ Wq, const float* __restrict__ bq,
    const float* __restrict__ Wk, const float* __restrict__ bk,
    const float* __restrict__ Wo,
    float* __restrict__ qp, float* __restrict__ kp_t,
    unsigned* __restrict__ mvt_u, unsigned* __restrict__ wob_u)
{
    __shared__ float smem[16 * 128 + 32 * 130];
    const int bid = blockIdx.x;
    const int t   = threadIdx.x;

    if (bid < NB_PROJ) {
        float* in16 = smem;
        float* Wt   = smem + 2048;
        const int r0 = bid * 16;
        const bool isQ = (r0 < 2048);
        const float4* src4 = (const float4*)(isQ ? (query + r0 * 128)
                                                 : (key + (r0 - 2048) * 128));
        {
            float4* in4 = (float4*)in16;
            in4[t]       = src4[t];
            in4[t + 256] = src4[t + 256];
        }
        const float* Wsrc = isQ ? Wq : Wk;
        const int j  = t & 127;
        const int rg = (t >> 7) * 8;
        const float bias = isQ ? bq[j] : bk[j];
        float acc[8];
#pragma unroll
        for (int r = 0; r < 8; ++r) acc[r] = bias;

        for (int ic = 0; ic < 4; ++ic) {
            __syncthreads();
            {
                const int i4 = t & 7, jg = t >> 3;
#pragma unroll
                for (int jj = 0; jj < 4; ++jj) {
                    const int jw = jg + jj * 32;
                    const float4 w = *(const float4*)(Wsrc + jw * 128 + ic * 32 + i4 * 4);
                    Wt[(i4 * 4 + 0) * 130 + jw] = w.x;
                    Wt[(i4 * 4 + 1) * 130 + jw] = w.y;
                    Wt[(i4 * 4 + 2) * 130 + jw] = w.z;
                    Wt[(i4 * 4 + 3) * 130 + jw] = w.w;
                }
            }
            __syncthreads();
#pragma unroll 2
            for (int i4 = 0; i4 < 8; ++i4) {
                const float w0 = Wt[(i4 * 4 + 0) * 130 + j];
                const float w1 = Wt[(i4 * 4 + 1) * 130 + j];
                const float w2 = Wt[(i4 * 4 + 2) * 130 + j];
                const float w3 = Wt[(i4 * 4 + 3) * 130 + j];
#pragma unroll
                for (int r = 0; r < 8; ++r) {
                    const float4 xv = ((const float4*)(in16 + (rg + r) * 128))[ic * 8 + i4];
                    acc[r] = fmaf(xv.x, w0, fmaf(xv.y, w1, fmaf(xv.z, w2, fmaf(xv.w, w3, acc[r]))));
                }
            }
        }

        if (isQ) {
            const float scale = 0.17677669529663687f;  // 1/sqrt(32) folded in
#pragma unroll
            for (int r = 0; r < 8; ++r) qp[(r0 + rg + r) * 128 + j] = acc[r] * scale;
        } else {
#pragma unroll
            for (int r = 0; r < 8; ++r) {
                const int row = r0 - 2048 + rg + r;
                const int bb = row >> 8, k = row & 255;
                kp_t[(bb * 128 + j) * 256 + k] = acc[r];
            }
        }
    } else if (bid < NB_PROJ + NB_MVT) {
        const int bb = (bid - NB_PROJ) >> 2, kt = (bid - NB_PROJ) & 3;
        const int c4 = t & 15, kp2 = t >> 4;
#pragma unroll
        for (int rr = 0; rr < 2; ++rr) {
            const int kpair = kp2 + rr * 16;
            const int k0 = kt * 64 + kpair * 2;
            const float4 v0 = *(const float4*)(value + (bb * 256 + k0) * 64 + c4 * 4);
            const float4 v1 = *(const float4*)(value + (bb * 256 + k0 + 1) * 64 + c4 * 4);
            const int4   m0 = *(const int4*)(mask + (bb * 256 + k0) * 64 + c4 * 4);
            const int4   m1 = *(const int4*)(mask + (bb * 256 + k0 + 1) * 64 + c4 * 4);
            const float a0[4] = {v0.x, v0.y, v0.z, v0.w};
            const float a1[4] = {v1.x, v1.y, v1.z, v1.w};
            const int   i0[4] = {m0.x, m0.y, m0.z, m0.w};
            const int   i1[4] = {m1.x, m1.y, m1.z, m1.w};
#pragma unroll
            for (int cc = 0; cc < 4; ++cc) {
                const int c = c4 * 4 + cc;
                const unsigned mv = (f2bf(i1[cc] ? a1[cc] : 0.f) << 16)
                                  |  f2bf(i0[cc] ? a0[cc] : 0.f);
                const unsigned ff = ((i1[cc] ? 0x3F80u : 0u) << 16)
                                  |  (i0[cc] ? 0x3F80u : 0u);
                mvt_u[(bb * 128 + c) * 128 + kt * 32 + kpair]      = mv;
                mvt_u[(bb * 128 + 64 + c) * 128 + kt * 32 + kpair] = ff;
            }
        }
    } else {
        const int idx4 = (bid - NB_PROJ - NB_MVT) * 256 + t;   // 0..8191
        const float4 w = ((const float4*)Wo)[idx4];
        uint2 p;
        p.x = (f2bf(w.y) << 16) | f2bf(w.x);
        p.y = (f2bf(w.w) << 16) | f2bf(w.z);
        ((uint2*)wob_u)[idx4] = p;
    }
}

// ---------------------------------------------------------------------------
// Fused attention: block = (qtile4, b), wave = head. Grid 512 = 2 blocks/CU.
__global__ __launch_bounds__(256) void attn_kernel(
    const float* __restrict__ qp, const float* __restrict__ kp_t,
    const short* __restrict__ mvt_s, const short* __restrict__ wob_s,
    const float* __restrict__ bo, float* __restrict__ out)
{
    const int qt = blockIdx.x, b = blockIdx.y;
    const int q0 = qt * 4;
    const int t = threadIdx.x, h = t >> 6, L = t & 63;

    __shared__ float qs[NH * 32 * 4];      // qs[h][i][q], 2 KB
    __shared__ short es[NH * 4 * 264];     // es[h][q][k] bf16, 8.4 KB
    __shared__ short xs[4 * 264];          // xs[q][j] bf16, 2.1 KB

    // stage q: qs[h][i][q] = qp_scaled[b*128+q0+q][h*32+i]
    {
        const int j = t & 127, qg = t >> 7;
        const int hh = j >> 5, ii = j & 31;
#pragma unroll
        for (int e = 0; e < 2; ++e) {
            const int q = qg * 2 + e;
            qs[hh * 128 + ii * 4 + q] = qp[(b * 128 + q0 + q) * 128 + j];
        }
    }
    __syncthreads();

    // G1: scores fp32. Lane L covers k = L*4..+4 for 4 q of its head.
    float s[4][4];
#pragma unroll
    for (int q = 0; q < 4; ++q)
#pragma unroll
        for (int kk = 0; kk < 4; ++kk) s[q][kk] = 0.f;
    {
        const float* kpb = kp_t + (b * 128 + h * 32) * 256 + L * 4;
        const float* qb  = qs + h * 128;
#pragma unroll 4
        for (int i = 0; i < 32; ++i) {
            const float4 kv = *(const float4*)(kpb + i * 256);
            const float4 qa = *(const float4*)(qb + i * 4);     // broadcast
            const float qv[4] = {qa.x, qa.y, qa.z, qa.w};
            const float kw[4] = {kv.x, kv.y, kv.z, kv.w};
#pragma unroll
            for (int q = 0; q < 4; ++q)
#pragma unroll
                for (int kk = 0; kk < 4; ++kk)
                    s[q][kk] = fmaf(qv[q], kw[kk], s[q][kk]);
        }
    }

    // softmax per q: wave-wide max, exp, bf16 -> es (MFMA A-frag layout)
#pragma unroll
    for (int q = 0; q < 4; ++q) {
        float m = fmaxf(fmaxf(s[q][0], s[q][1]), fmaxf(s[q][2], s[q][3]));
#pragma unroll
        for (int off = 32; off > 0; off >>= 1) m = fmaxf(m, __shfl_xor(m, off, 64));
        const unsigned e01 = (f2bf(__expf(s[q][1] - m)) << 16) | f2bf(__expf(s[q][0] - m));
        const unsigned e23 = (f2bf(__expf(s[q][3] - m)) << 16) | f2bf(__expf(s[q][2] - m));
        *(uint2*)&es[h * 1056 + q * 264 + L * 4] = make_uint2(e01, e23);
    }
    // no barrier: es produced and consumed by the same wave

    // G2: PV via MFMA. D tiles 0..3 = num, 4..7 = den. A rows clamped to q&3
    // (rows 4..15 of D are duplicates, discarded) -> no garbage reads.
    const int lq = L & 15, lk = (L >> 4) * 8;
    floatx4 pv[8];
#pragma unroll
    for (int tt = 0; tt < 8; ++tt) pv[tt] = (floatx4){0.f, 0.f, 0.f, 0.f};
    {
        const short* eb = es + h * 1056 + (lq & 3) * 264;
        const short* mb = mvt_s + (b * 128) * 256 + lk;
#pragma unroll
        for (int c8 = 0; c8 < 8; ++c8) {
            const short8 a = *(const short8*)(eb + c8 * 32 + lk);
#pragma unroll
            for (int tt = 0; tt < 8; ++tt) {
                const short8 bf = *(const short8*)(mb + (tt * 16 + lq) * 256 + c8 * 32);
                pv[tt] = __builtin_amdgcn_mfma_f32_16x16x32_bf16(a, bf, pv[tt], 0, 0, 0);
            }
        }
    }
    // x = num/den -> xs[q][h*64+c] bf16 (rows 0..3)
    if ((L >> 4) == 0) {
#pragma unroll
        for (int tt = 0; tt < 4; ++tt)
#pragma unroll
            for (int r = 0; r < 4; ++r)
                xs[r * 264 + h * 64 + tt * 16 + lq] =
                    (short)f2bf(pv[tt][r] / pv[tt + 4][r]);
    }
    __syncthreads();

    // G3: O-projection via MFMA, full K=256 -> direct store (no atomics)
    floatx4 oa[2];
    oa[0] = (floatx4){0.f, 0.f, 0.f, 0.f};
    oa[1] = (floatx4){0.f, 0.f, 0.f, 0.f};
    {
        const short* xb = xs + (lq & 3) * 264;
#pragma unroll
        for (int j8 = 0; j8 < 8; ++j8) {
            const short8 a = *(const short8*)(xb + j8 * 32 + lk);
#pragma unroll
            for (int w = 0; w < 2; ++w) {
                const int o = (h * 2 + w) * 16 + lq;
                const short8 bf = *(const short8*)(wob_s + o * 256 + j8 * 32 + lk);
                oa[w] = __builtin_amdgcn_mfma_f32_16x16x32_bf16(a, bf, oa[w], 0, 0, 0);
            }
        }
    }
    if ((L >> 4) == 0) {
#pragma unroll
        for (int w = 0; w < 2; ++w) {
            const int o = (h * 2 + w) * 16 + lq;
            const float bov = bo[o];
#pragma unroll
            for (int r = 0; r < 4; ++r)
                out[(b * 128 + q0 + r) * 128 + o] = oa[w][r] + bov;
        }
    }
}

extern "C" void kernel_launch(void* const* d_in, const int* in_sizes, int n_in,
                              void* d_out, int out_size, void* d_ws, size_t ws_size,
                              hipStream_t stream)
{
    const float* query = (const float*)d_in[0];
    const float* key   = (const float*)d_in[1];
    const float* value = (const float*)d_in[2];
    const int*   mask  = (const int*)d_in[3];
    const float* Wq    = (const float*)d_in[4];
    const float* bq    = (const float*)d_in[5];
    const float* Wk    = (const float*)d_in[6];
    const float* bk    = (const float*)d_in[7];
    const float* Wo    = (const float*)d_in[8];
    const float* bo    = (const float*)d_in[9];
    float* out = (float*)d_out;

    float* ws       = (float*)d_ws;
    float* qp       = ws;                           // 262144 f32
    float* kp_t     = qp + 262144;                  // 524288 f32
    unsigned* mvt_u = (unsigned*)(kp_t + 524288);   // 262144 u32
    unsigned* wob_u = mvt_u + 262144;               // 16384 u32

    setup_kernel<<<NB_SETUP, 256, 0, stream>>>(query, key, value, mask,
                                               Wq, bq, Wk, bk, Wo,
                                               qp, kp_t, mvt_u, wob_u);
    attn_kernel<<<dim3(32, B), 256, 0, stream>>>(qp, kp_t,
                                                 (const short*)mvt_u,
                                                 (const short*)wob_u, bo, out);
}